// Round 1
// baseline (295.301 us; speedup 1.0000x reference)
//
#include <hip/hip_runtime.h>
#include <stdint.h>

#define M_DIM 4096
#define T_DIM 2048
#define N_OUT 2024
#define N_PAD 2048
#define WIN   25
#define K_DIM 4096

typedef short bf16x8 __attribute__((ext_vector_type(8)));
typedef float f32x4  __attribute__((ext_vector_type(4)));

__device__ __forceinline__ unsigned short f2bf(float x) {
  unsigned u = __float_as_uint(x);
  u += 0x7FFF + ((u >> 16) & 1);           // round-to-nearest-even
  return (unsigned short)(u >> 16);
}
__device__ __forceinline__ float bf2f(unsigned short h) {
  return __uint_as_float(((unsigned)h) << 16);
}

__device__ __forceinline__ void gl2lds16(const void* g, void* l) {
  // 16B-wide async global->LDS; LDS dest is wave-uniform base + lane*16
  __builtin_amdgcn_global_load_lds(
      (const __attribute__((address_space(1))) unsigned int*)g,
      (__attribute__((address_space(3))) unsigned int*)l, 16, 0, 0);
}

// ---------- Kernel 1: Wb = bf16(sigmoid(alphas)), diagonal -> 0 ----------
__global__ __launch_bounds__(256) void k_wcast(const float* __restrict__ alphas,
                                               unsigned short* __restrict__ Wb) {
  size_t i4 = ((size_t)blockIdx.x * 256 + threadIdx.x) * 4;
  const float4 v = *(const float4*)(alphas + i4);
  int row = (int)(i4 >> 12);
  int col = (int)(i4 & 4095);
  float a[4] = {v.x, v.y, v.z, v.w};
  ushort4 o;
  unsigned short* op = (unsigned short*)&o;
#pragma unroll
  for (int j = 0; j < 4; ++j) {
    float w = (row == col + j) ? 0.f : 1.f / (1.f + __expf(-a[j]));
    op[j] = f2bf(w);
  }
  *(ushort4*)(Wb + i4) = o;
}

// ---------- Kernel 2: S = bf16(softplus(depthwise_conv(ys, repro))) ----------
__global__ __launch_bounds__(256) void k_conv(const float* __restrict__ ys,
                                              const float* __restrict__ repro,
                                              unsigned short* __restrict__ Sbf) {
  __shared__ float sy[256 + WIN - 1];
  __shared__ float sr[WIN];
  int m = blockIdx.y;
  int j0 = blockIdx.x * 256;
  int tid = threadIdx.x;
  sy[tid] = ys[(size_t)m * T_DIM + j0 + tid];
  if (tid < WIN - 1) {
    int jj = j0 + 256 + tid;
    sy[256 + tid] = (jj < T_DIM) ? ys[(size_t)m * T_DIM + jj] : 0.f;
  }
  if (tid < WIN) sr[tid] = repro[m * WIN + tid];
  __syncthreads();
  int j = j0 + tid;
  float z = 0.f;
#pragma unroll
  for (int k = 0; k < WIN; ++k) z += sy[tid + k] * sr[k];
  float sp = fmaxf(z, 0.f) + log1pf(__expf(-fabsf(z)));
  Sbf[(size_t)m * N_PAD + j] = (j < N_OUT) ? f2bf(sp) : (unsigned short)0;
}

// ---------- Kernel 3: BT[n][k] = bf16(ys[k][n+24]), zero-pad n>=2024 ----------
__global__ __launch_bounds__(256) void k_transpose(const float* __restrict__ ys,
                                                   unsigned short* __restrict__ BT) {
  __shared__ float t[32][33];
  int n0 = blockIdx.x * 32;
  int k0 = blockIdx.y * 32;
  int tx = threadIdx.x;  // 0..31
  int ty = threadIdx.y;  // 0..7
#pragma unroll
  for (int r = 0; r < 4; ++r) {
    int kk = k0 + ty + r * 8;
    int n = n0 + tx;
    t[ty + r * 8][tx] = (n < N_OUT) ? ys[(size_t)kk * T_DIM + n + (WIN - 1)] : 0.f;
  }
  __syncthreads();
#pragma unroll
  for (int r = 0; r < 4; ++r) {
    int n = n0 + ty + r * 8;
    int kk = k0 + tx;
    BT[(size_t)n * K_DIM + kk] = f2bf(t[tx][ty + r * 8]);
  }
}

// ---------- Kernel 4: C = Wb @ BT^T, out = beta * (S + C) ----------
__global__ __launch_bounds__(256) void k_gemm(const unsigned short* __restrict__ Wb,
                                              const unsigned short* __restrict__ BT,
                                              const unsigned short* __restrict__ Sbf,
                                              const float* __restrict__ b0,
                                              const float* __restrict__ b1,
                                              float* __restrict__ out) {
  __shared__ __align__(16) unsigned short lA[128 * 32];
  __shared__ __align__(16) unsigned short lB[128 * 32];
  const int tid  = threadIdx.x;
  const int wave = tid >> 6;
  const int lane = tid & 63;
  const int wm = wave >> 1, wn = wave & 1;
  const int m16  = lane & 15;
  const int quad = lane >> 4;
  const int kof  = quad * 8;
  const int tileM = blockIdx.y * 128;
  const int tileN = blockIdx.x * 128;

  f32x4 acc[4][4];
#pragma unroll
  for (int i = 0; i < 4; ++i)
#pragma unroll
    for (int j = 0; j < 4; ++j) acc[i][j] = f32x4{0.f, 0.f, 0.f, 0.f};

  for (int kt = 0; kt < K_DIM / 32; ++kt) {
    const int k0 = kt * 32;
#pragma unroll
    for (int c = 0; c < 2; ++c) {
      int f = c * 256 + tid;            // 16B chunk index, 0..511
      int row = f >> 2;                 // 64 B per row (32 bf16)
      int colb = (f & 3) << 4;          // byte offset within row
      const char* gA = (const char*)Wb + (((size_t)(tileM + row) * K_DIM + k0) << 1) + colb;
      const char* gB = (const char*)BT + (((size_t)(tileN + row) * K_DIM + k0) << 1) + colb;
      gl2lds16(gA, (char*)lA + c * 4096 + wave * 1024);
      gl2lds16(gB, (char*)lB + c * 4096 + wave * 1024);
    }
    __syncthreads();
    bf16x8 aF[4], bF[4];
#pragma unroll
    for (int i = 0; i < 4; ++i) {
      aF[i] = *(const bf16x8*)&lA[(wm * 64 + i * 16 + m16) * 32 + kof];
      bF[i] = *(const bf16x8*)&lB[(wn * 64 + i * 16 + m16) * 32 + kof];
    }
#pragma unroll
    for (int i = 0; i < 4; ++i)
#pragma unroll
      for (int j = 0; j < 4; ++j)
        acc[i][j] = __builtin_amdgcn_mfma_f32_16x16x32_bf16(aF[i], bF[j], acc[i][j], 0, 0, 0);
    __syncthreads();
  }

  // Epilogue: out[gm][gn] = softplus(b0+b1*(gn+25)) * (S[gm][gn] + C)
#pragma unroll
  for (int j = 0; j < 4; ++j) {
    int gn = tileN + wn * 64 + j * 16 + m16;
    if (gn >= N_OUT) continue;
    float tval = (float)(gn + WIN);     // t index after VALID offset: j+25
#pragma unroll
    for (int i = 0; i < 4; ++i) {
#pragma unroll
      for (int r = 0; r < 4; ++r) {
        int gm = tileM + wm * 64 + i * 16 + quad * 4 + r;
        float x = b0[gm] + b1[gm] * tval;
        float beta = fmaxf(x, 0.f) + log1pf(__expf(-fabsf(x)));
        float s = bf2f(Sbf[(size_t)gm * N_PAD + gn]);
        out[(size_t)gm * N_OUT + gn] = beta * (s + acc[i][j][r]);
      }
    }
  }
}

extern "C" void kernel_launch(void* const* d_in, const int* in_sizes, int n_in,
                              void* d_out, int out_size, void* d_ws, size_t ws_size,
                              hipStream_t stream) {
  const float* ys     = (const float*)d_in[0];
  const float* alphas = (const float*)d_in[1];
  const float* repro  = (const float*)d_in[2];
  const float* b0     = (const float*)d_in[3];
  const float* b1     = (const float*)d_in[4];
  float* out = (float*)d_out;

  char* ws = (char*)d_ws;
  unsigned short* Wb  = (unsigned short*)ws;                                   // 32 MiB
  unsigned short* BT  = (unsigned short*)(ws + (size_t)M_DIM * K_DIM * 2);     // 16 MiB
  unsigned short* Sbf = (unsigned short*)(ws + (size_t)M_DIM * K_DIM * 2
                                             + (size_t)N_PAD * K_DIM * 2);     // 16 MiB

  k_wcast<<<(M_DIM * (size_t)K_DIM) / 4 / 256, 256, 0, stream>>>(alphas, Wb);
  k_conv<<<dim3(T_DIM / 256, M_DIM), 256, 0, stream>>>(ys, repro, Sbf);
  k_transpose<<<dim3(N_PAD / 32, K_DIM / 32), dim3(32, 8), 0, stream>>>(ys, BT);
  k_gemm<<<dim3(N_PAD / 128, M_DIM / 128), 256, 0, stream>>>(Wb, BT, Sbf, b0, b1, out);
}

// Round 2
// 294.881 us; speedup vs baseline: 1.0014x; 1.0014x over previous
//
#include <hip/hip_runtime.h>
#include <stdint.h>

#define M_DIM 4096
#define T_DIM 2048
#define N_OUT 2024
#define N_PAD 2048
#define WIN   25
#define K_DIM 4096

typedef short bf16x8 __attribute__((ext_vector_type(8)));
typedef float f32x4  __attribute__((ext_vector_type(4)));

__device__ __forceinline__ unsigned short f2bf(float x) {
  unsigned u = __float_as_uint(x);
  u += 0x7FFF + ((u >> 16) & 1);           // round-to-nearest-even
  return (unsigned short)(u >> 16);
}
__device__ __forceinline__ float bf2f(unsigned short h) {
  return __uint_as_float(((unsigned)h) << 16);
}

__device__ __forceinline__ void gl2lds16(const void* g, void* l) {
  // 16B-wide async global->LDS; HW dest = wave-uniform base + lane*16
  __builtin_amdgcn_global_load_lds(
      (const __attribute__((address_space(1))) unsigned int*)g,
      (__attribute__((address_space(3))) unsigned int*)l, 16, 0, 0);
}

// ---------- Kernel 1: Wb = bf16(sigmoid(alphas)), diagonal -> 0 ----------
// 8 elements/thread: 2x float4 load, 1x 16B store
__global__ __launch_bounds__(256) void k_wcast(const float* __restrict__ alphas,
                                               unsigned short* __restrict__ Wb) {
  size_t i8 = ((size_t)blockIdx.x * 256 + threadIdx.x) * 8;
  const float4 v0 = *(const float4*)(alphas + i8);
  const float4 v1 = *(const float4*)(alphas + i8 + 4);
  int row = (int)(i8 >> 12);
  int col = (int)(i8 & 4095);
  float a[8] = {v0.x, v0.y, v0.z, v0.w, v1.x, v1.y, v1.z, v1.w};
  ushort4 o[2];
  unsigned short* op = (unsigned short*)o;
#pragma unroll
  for (int j = 0; j < 8; ++j) {
    float w = (row == col + j) ? 0.f : 1.f / (1.f + __expf(-a[j]));
    op[j] = f2bf(w);
  }
  *(uint4*)(Wb + i8) = *(uint4*)o;
}

// ---------- Kernel 2: S = bf16(softplus(depthwise_conv(ys, repro))) ----------
__global__ __launch_bounds__(256) void k_conv(const float* __restrict__ ys,
                                              const float* __restrict__ repro,
                                              unsigned short* __restrict__ Sbf) {
  __shared__ float sy[256 + WIN - 1];
  __shared__ float sr[WIN];
  int m = blockIdx.y;
  int j0 = blockIdx.x * 256;
  int tid = threadIdx.x;
  sy[tid] = ys[(size_t)m * T_DIM + j0 + tid];
  if (tid < WIN - 1) {
    int jj = j0 + 256 + tid;
    sy[256 + tid] = (jj < T_DIM) ? ys[(size_t)m * T_DIM + jj] : 0.f;
  }
  if (tid < WIN) sr[tid] = repro[m * WIN + tid];
  __syncthreads();
  int j = j0 + tid;
  float z = 0.f;
#pragma unroll
  for (int k = 0; k < WIN; ++k) z += sy[tid + k] * sr[k];
  float sp = fmaxf(z, 0.f) + log1pf(__expf(-fabsf(z)));
  Sbf[(size_t)m * N_PAD + j] = (j < N_OUT) ? f2bf(sp) : (unsigned short)0;
}

// ---------- Kernel 3: BT[n][k] = bf16(ys[k][n+24]), zero-pad n>=2024 ----------
__global__ __launch_bounds__(256) void k_transpose(const float* __restrict__ ys,
                                                   unsigned short* __restrict__ BT) {
  __shared__ float t[32][33];
  int n0 = blockIdx.x * 32;
  int k0 = blockIdx.y * 32;
  int tx = threadIdx.x;  // 0..31
  int ty = threadIdx.y;  // 0..7
#pragma unroll
  for (int r = 0; r < 4; ++r) {
    int kk = k0 + ty + r * 8;
    int n = n0 + tx;
    t[ty + r * 8][tx] = (n < N_OUT) ? ys[(size_t)kk * T_DIM + n + (WIN - 1)] : 0.f;
  }
  __syncthreads();
#pragma unroll
  for (int r = 0; r < 4; ++r) {
    int n = n0 + ty + r * 8;
    int kk = k0 + tx;
    BT[(size_t)n * K_DIM + kk] = f2bf(t[tx][ty + r * 8]);
  }
}

// ---------- Kernel 4: C = Wb @ BT^T, out = beta * (S + C) ----------
// 512 threads = 8 waves (2x4 wave grid); wave computes 64Mx32N (acc[4][2]).
// Same 128x128 tile / 512-block grid, but 16 waves/CU instead of 8.
__global__ __launch_bounds__(512, 4) void k_gemm(const unsigned short* __restrict__ Wb,
                                                 const unsigned short* __restrict__ BT,
                                                 const unsigned short* __restrict__ Sbf,
                                                 const float* __restrict__ b0,
                                                 const float* __restrict__ b1,
                                                 float* __restrict__ out) {
  __shared__ __align__(16) unsigned short lA[128 * 32];
  __shared__ __align__(16) unsigned short lB[128 * 32];
  const int tid  = threadIdx.x;
  const int wave = tid >> 6;          // 0..7
  const int lane = tid & 63;
  const int wm = wave >> 2;           // 0..1 (M)
  const int wn = wave & 3;            // 0..3 (N)
  const int m16  = lane & 15;
  const int quad = lane >> 4;
  const int kof  = quad * 8;
  const int tileM = blockIdx.y * 128;
  const int tileN = blockIdx.x * 128;

  // staging: 512 chunks of 16B per matrix, one chunk each per thread
  const int srow  = tid >> 2;         // 0..127
  const int scolb = (tid & 3) << 4;   // byte offset in 64B row

  f32x4 acc[4][2];
#pragma unroll
  for (int i = 0; i < 4; ++i)
#pragma unroll
    for (int j = 0; j < 2; ++j) acc[i][j] = f32x4{0.f, 0.f, 0.f, 0.f};

  const char* gA0 = (const char*)Wb + (((size_t)(tileM + srow) * K_DIM) << 1) + scolb;
  const char* gB0 = (const char*)BT + (((size_t)(tileN + srow) * K_DIM) << 1) + scolb;

  for (int kt = 0; kt < K_DIM / 32; ++kt) {
    const size_t kb = (size_t)kt * 64;  // 32 bf16 = 64 bytes per k-tile row
    gl2lds16(gA0 + kb, (char*)lA + wave * 1024);
    gl2lds16(gB0 + kb, (char*)lB + wave * 1024);
    __syncthreads();
    bf16x8 aF[4], bF[2];
#pragma unroll
    for (int i = 0; i < 4; ++i)
      aF[i] = *(const bf16x8*)&lA[(wm * 64 + i * 16 + m16) * 32 + kof];
#pragma unroll
    for (int j = 0; j < 2; ++j)
      bF[j] = *(const bf16x8*)&lB[(wn * 32 + j * 16 + m16) * 32 + kof];
#pragma unroll
    for (int i = 0; i < 4; ++i)
#pragma unroll
      for (int j = 0; j < 2; ++j)
        acc[i][j] = __builtin_amdgcn_mfma_f32_16x16x32_bf16(aF[i], bF[j], acc[i][j], 0, 0, 0);
    __syncthreads();
  }

  // Epilogue: out[gm][gn] = softplus(b0+b1*(gn+25)) * (S[gm][gn] + C)
#pragma unroll
  for (int j = 0; j < 2; ++j) {
    int gn = tileN + wn * 32 + j * 16 + m16;
    if (gn >= N_OUT) continue;
    float tval = (float)(gn + WIN);
#pragma unroll
    for (int i = 0; i < 4; ++i) {
#pragma unroll
      for (int r = 0; r < 4; ++r) {
        int gm = tileM + wm * 64 + i * 16 + quad * 4 + r;
        float x = b0[gm] + b1[gm] * tval;
        float beta = fmaxf(x, 0.f) + log1pf(__expf(-fabsf(x)));
        float s = bf2f(Sbf[(size_t)gm * N_PAD + gn]);
        out[(size_t)gm * N_OUT + gn] = beta * (s + acc[i][j][r]);
      }
    }
  }
}

extern "C" void kernel_launch(void* const* d_in, const int* in_sizes, int n_in,
                              void* d_out, int out_size, void* d_ws, size_t ws_size,
                              hipStream_t stream) {
  const float* ys     = (const float*)d_in[0];
  const float* alphas = (const float*)d_in[1];
  const float* repro  = (const float*)d_in[2];
  const float* b0     = (const float*)d_in[3];
  const float* b1     = (const float*)d_in[4];
  float* out = (float*)d_out;

  char* ws = (char*)d_ws;
  unsigned short* Wb  = (unsigned short*)ws;                                   // 32 MiB
  unsigned short* BT  = (unsigned short*)(ws + (size_t)M_DIM * K_DIM * 2);     // 16 MiB
  unsigned short* Sbf = (unsigned short*)(ws + (size_t)M_DIM * K_DIM * 2
                                             + (size_t)N_PAD * K_DIM * 2);     // 16 MiB

  k_wcast<<<(M_DIM * (size_t)K_DIM) / 8 / 256, 256, 0, stream>>>(alphas, Wb);
  k_conv<<<dim3(T_DIM / 256, M_DIM), 256, 0, stream>>>(ys, repro, Sbf);
  k_transpose<<<dim3(N_PAD / 32, K_DIM / 32), dim3(32, 8), 0, stream>>>(ys, BT);
  k_gemm<<<dim3(N_PAD / 128, M_DIM / 128), 512, 0, stream>>>(Wb, BT, Sbf, b0, b1, out);
}

// Round 3
// 287.878 us; speedup vs baseline: 1.0258x; 1.0243x over previous
//
#include <hip/hip_runtime.h>
#include <stdint.h>

#define M_DIM 4096
#define T_DIM 2048
#define N_OUT 2024
#define N_PAD 2048
#define WIN   25
#define K_DIM 4096

typedef short bf16x8 __attribute__((ext_vector_type(8)));
typedef float f32x4  __attribute__((ext_vector_type(4)));

__device__ __forceinline__ unsigned short f2bf(float x) {
  unsigned u = __float_as_uint(x);
  u += 0x7FFF + ((u >> 16) & 1);           // round-to-nearest-even
  return (unsigned short)(u >> 16);
}
__device__ __forceinline__ float bf2f(unsigned short h) {
  return __uint_as_float(((unsigned)h) << 16);
}

__device__ __forceinline__ void gl2lds16(const void* g, void* l) {
  // 16B-wide async global->LDS; HW dest = wave-uniform base + lane*16
  __builtin_amdgcn_global_load_lds(
      (const __attribute__((address_space(1))) unsigned int*)g,
      (__attribute__((address_space(3))) unsigned int*)l, 16, 0, 0);
}

// ---------- Kernel 1: Wb = bf16(sigmoid(alphas)), diagonal -> 0 ----------
__global__ __launch_bounds__(256) void k_wcast(const float* __restrict__ alphas,
                                               unsigned short* __restrict__ Wb) {
  size_t i8 = ((size_t)blockIdx.x * 256 + threadIdx.x) * 8;
  const float4 v0 = *(const float4*)(alphas + i8);
  const float4 v1 = *(const float4*)(alphas + i8 + 4);
  int row = (int)(i8 >> 12);
  int col = (int)(i8 & 4095);
  float a[8] = {v0.x, v0.y, v0.z, v0.w, v1.x, v1.y, v1.z, v1.w};
  ushort4 o[2];
  unsigned short* op = (unsigned short*)o;
#pragma unroll
  for (int j = 0; j < 8; ++j) {
    float w = (row == col + j) ? 0.f : 1.f / (1.f + __expf(-a[j]));
    op[j] = f2bf(w);
  }
  *(uint4*)(Wb + i8) = *(uint4*)o;
}

// ---------- Kernel 2: S = bf16(softplus(depthwise_conv(ys, repro))) ----------
__global__ __launch_bounds__(256) void k_conv(const float* __restrict__ ys,
                                              const float* __restrict__ repro,
                                              unsigned short* __restrict__ Sbf) {
  __shared__ float sy[256 + WIN - 1];
  __shared__ float sr[WIN];
  int m = blockIdx.y;
  int j0 = blockIdx.x * 256;
  int tid = threadIdx.x;
  sy[tid] = ys[(size_t)m * T_DIM + j0 + tid];
  if (tid < WIN - 1) {
    int jj = j0 + 256 + tid;
    sy[256 + tid] = (jj < T_DIM) ? ys[(size_t)m * T_DIM + jj] : 0.f;
  }
  if (tid < WIN) sr[tid] = repro[m * WIN + tid];
  __syncthreads();
  int j = j0 + tid;
  float z = 0.f;
#pragma unroll
  for (int k = 0; k < WIN; ++k) z += sy[tid + k] * sr[k];
  float sp = fmaxf(z, 0.f) + log1pf(__expf(-fabsf(z)));
  Sbf[(size_t)m * N_PAD + j] = (j < N_OUT) ? f2bf(sp) : (unsigned short)0;
}

// ---------- Kernel 3: BT[n][k] = bf16(ys[k][n+24]), zero-pad n>=2024 ----------
// 64x64 tiles: 256B coalesced reads, 128B coalesced writes
__global__ __launch_bounds__(256) void k_transpose(const float* __restrict__ ys,
                                                   unsigned short* __restrict__ BT) {
  __shared__ float t[64][65];
  int n0 = blockIdx.x * 64;
  int k0 = blockIdx.y * 64;
  int tx = threadIdx.x;  // 0..63
  int ty = threadIdx.y;  // 0..3
#pragma unroll
  for (int r = 0; r < 16; ++r) {
    int kk = k0 + ty + r * 4;
    int n = n0 + tx;
    t[ty + r * 4][tx] = (n < N_OUT) ? ys[(size_t)kk * T_DIM + n + (WIN - 1)] : 0.f;
  }
  __syncthreads();
#pragma unroll
  for (int r = 0; r < 16; ++r) {
    int n = n0 + ty + r * 4;
    int kk = k0 + tx;
    BT[(size_t)n * K_DIM + kk] = f2bf(t[tx][ty + r * 4]);
  }
}

// ---------- Kernel 4: C = Wb @ BT^T, out = beta * (S + C) ----------
// 256 threads = 4 waves (2x2), wave tile 64x64 (acc[4][4]).
// LDS rows hold BK=32 bf16 (64B = 4 x 16B chunks); chunk c of row r is stored
// at chunk slot c ^ ((r>>1)&3)  (XOR swizzle applied on the GLOBAL source
// address, since global_load_lds forces lane-contiguous LDS writes).
// Fragment reads then hit all 8 bank-groups 2-way => conflict-free.
__global__ __launch_bounds__(256) void k_gemm(const unsigned short* __restrict__ Wb,
                                              const unsigned short* __restrict__ BT,
                                              const unsigned short* __restrict__ Sbf,
                                              const float* __restrict__ b0,
                                              const float* __restrict__ b1,
                                              float* __restrict__ out) {
  __shared__ __align__(16) unsigned short lA[128 * 32];
  __shared__ __align__(16) unsigned short lB[128 * 32];
  const int tid  = threadIdx.x;
  const int wave = tid >> 6;          // 0..3
  const int lane = tid & 63;
  const int wm = wave >> 1, wn = wave & 1;
  const int m16  = lane & 15;
  const int quad = lane >> 4;
  const int tileM = blockIdx.y * 128;
  const int tileN = blockIdx.x * 128;

  // ---- read-side swizzled fragment offsets (bytes) ----
  const int swz   = ((quad ^ ((m16 >> 1) & 3)) << 4);      // swizzled 16B chunk
  const int offA0 = (wm * 64 + m16) * 64 + swz;            // + i*1024
  const int offB0 = (wn * 64 + m16) * 64 + swz;            // + j*1024

  // ---- staging: 2 chunks/thread/matrix; global addr carries the swizzle ----
  // chunk c in {0,1}: lds byte offset o = c*4096 + wave*1024 + lane*16
  const char* gA[2];
  const char* gB[2];
  char* ldsA[2];
  char* ldsB[2];
#pragma unroll
  for (int c = 0; c < 2; ++c) {
    int o  = c * 4096 + wave * 1024 + lane * 16;
    int r  = o >> 6;                    // LDS row 0..127
    int cc = (o >> 4) & 3;              // LDS chunk slot
    int q  = cc ^ ((r >> 1) & 3);       // logical (global) chunk
    gA[c] = (const char*)Wb + (((size_t)(tileM + r) * K_DIM) << 1) + q * 16;
    gB[c] = (const char*)BT + (((size_t)(tileN + r) * K_DIM) << 1) + q * 16;
    ldsA[c] = (char*)lA + c * 4096 + wave * 1024;   // wave-uniform base
    ldsB[c] = (char*)lB + c * 4096 + wave * 1024;
  }

  f32x4 acc[4][4];
#pragma unroll
  for (int i = 0; i < 4; ++i)
#pragma unroll
    for (int j = 0; j < 4; ++j) acc[i][j] = f32x4{0.f, 0.f, 0.f, 0.f};

  for (int kt = 0; kt < K_DIM / 32; ++kt) {
    const size_t kb = (size_t)kt * 64;  // 32 bf16 = 64 bytes
#pragma unroll
    for (int c = 0; c < 2; ++c) {
      gl2lds16(gA[c] + kb, ldsA[c]);
      gl2lds16(gB[c] + kb, ldsB[c]);
    }
    __syncthreads();
    bf16x8 aF[4], bF[4];
#pragma unroll
    for (int i = 0; i < 4; ++i) {
      aF[i] = *(const bf16x8*)((const char*)lA + offA0 + i * 1024);
      bF[i] = *(const bf16x8*)((const char*)lB + offB0 + i * 1024);
    }
#pragma unroll
    for (int i = 0; i < 4; ++i)
#pragma unroll
      for (int j = 0; j < 4; ++j)
        acc[i][j] = __builtin_amdgcn_mfma_f32_16x16x32_bf16(aF[i], bF[j], acc[i][j], 0, 0, 0);
    __syncthreads();
  }

  // Epilogue: out[gm][gn] = softplus(b0+b1*(gn+25)) * (S[gm][gn] + C)
#pragma unroll
  for (int j = 0; j < 4; ++j) {
    int gn = tileN + wn * 64 + j * 16 + m16;
    if (gn >= N_OUT) continue;
    float tval = (float)(gn + WIN);
#pragma unroll
    for (int i = 0; i < 4; ++i) {
#pragma unroll
      for (int r = 0; r < 4; ++r) {
        int gm = tileM + wm * 64 + i * 16 + quad * 4 + r;
        float x = b0[gm] + b1[gm] * tval;
        float beta = fmaxf(x, 0.f) + log1pf(__expf(-fabsf(x)));
        float s = bf2f(Sbf[(size_t)gm * N_PAD + gn]);
        out[(size_t)gm * N_OUT + gn] = beta * (s + acc[i][j][r]);
      }
    }
  }
}

extern "C" void kernel_launch(void* const* d_in, const int* in_sizes, int n_in,
                              void* d_out, int out_size, void* d_ws, size_t ws_size,
                              hipStream_t stream) {
  const float* ys     = (const float*)d_in[0];
  const float* alphas = (const float*)d_in[1];
  const float* repro  = (const float*)d_in[2];
  const float* b0     = (const float*)d_in[3];
  const float* b1     = (const float*)d_in[4];
  float* out = (float*)d_out;

  char* ws = (char*)d_ws;
  unsigned short* Wb  = (unsigned short*)ws;                                   // 32 MiB
  unsigned short* BT  = (unsigned short*)(ws + (size_t)M_DIM * K_DIM * 2);     // 16 MiB
  unsigned short* Sbf = (unsigned short*)(ws + (size_t)M_DIM * K_DIM * 2
                                             + (size_t)N_PAD * K_DIM * 2);     // 16 MiB

  k_wcast<<<(M_DIM * (size_t)K_DIM) / 8 / 256, 256, 0, stream>>>(alphas, Wb);
  k_conv<<<dim3(T_DIM / 256, M_DIM), 256, 0, stream>>>(ys, repro, Sbf);
  k_transpose<<<dim3(N_PAD / 64, K_DIM / 64), dim3(64, 4), 0, stream>>>(ys, BT);
  k_gemm<<<dim3(N_PAD / 128, M_DIM / 128), 256, 0, stream>>>(Wb, BT, Sbf, b0, b1, out);
}